// Round 1
// baseline (479.373 us; speedup 1.0000x reference)
//
#include <hip/hip_runtime.h>
#include <stdint.h>

#define B 16
#define N 20000
#define D 256
#define K 300

// ---------------------------------------------------------------------------
// Kernel 1: per-token score = dot(token, W) + b, stored as a monotone uint32
// key (order-preserving float->uint transform) so top-k can radix-select.
// One wave (64 lanes) per token: lane l loads float4 at [l*4..l*4+3].
// ---------------------------------------------------------------------------
__global__ __launch_bounds__(256) void score_kernel(
    const float* __restrict__ tokens, const float* __restrict__ W,
    const float* __restrict__ bias, uint32_t* __restrict__ keys) {
  int gwave = (blockIdx.x * blockDim.x + threadIdx.x) >> 6;
  int lane = threadIdx.x & 63;
  if (gwave >= B * N) return;
  const float4 w4 = ((const float4*)W)[lane];
  const float4 t4 = ((const float4*)(tokens + (size_t)gwave * D))[lane];
  float dot = t4.x * w4.x + t4.y * w4.y + t4.z * w4.z + t4.w * w4.w;
#pragma unroll
  for (int off = 32; off >= 1; off >>= 1) dot += __shfl_xor(dot, off, 64);
  if (lane == 0) {
    float s = dot + bias[0];
    uint32_t u = __float_as_uint(s);
    keys[gwave] = (u & 0x80000000u) ? ~u : (u | 0x80000000u);
  }
}

// ---------------------------------------------------------------------------
// Kernel 2: per-batch top-K via MSB-first radix select on uint32 keys, then
// collect all keys >= threshold and bitonic-sort (key desc, idx asc).
// One block of 1024 threads per batch.
// ---------------------------------------------------------------------------
__global__ __launch_bounds__(1024) void topk_kernel(
    const uint32_t* __restrict__ keys_g, int* __restrict__ idx_out,
    float* __restrict__ out_idx_f) {
  __shared__ uint32_t hist[256];
  __shared__ uint32_t s_prefix, s_remaining, cand_cnt;
  __shared__ uint64_t cand[512];

  const int b = blockIdx.x;
  const int t = threadIdx.x;
  const uint32_t* keys = keys_g + (size_t)b * N;

  if (t == 0) {
    s_prefix = 0;
    s_remaining = K;
    cand_cnt = 0;
  }
  __syncthreads();

  // 4 radix passes, MSB first: find threshold key T such that
  // count(key > T) < K <= count(key >= T).
  for (int pass = 0; pass < 4; ++pass) {
    int shift = 24 - pass * 8;
    if (t < 256) hist[t] = 0;
    __syncthreads();
    uint32_t prefix = s_prefix;
    uint32_t pmask = (pass == 0) ? 0u : (0xFFFFFFFFu << (shift + 8));
    for (int i = t; i < N; i += 1024) {
      uint32_t k = keys[i];
      if ((k & pmask) == prefix) atomicAdd(&hist[(k >> shift) & 0xFFu], 1u);
    }
    __syncthreads();
    if (t == 0) {
      uint32_t rem = s_remaining;
      uint32_t acc = 0;
      int bin = 255;
      for (; bin > 0; --bin) {
        if (acc + hist[bin] >= rem) break;
        acc += hist[bin];
      }
      s_prefix = prefix | ((uint32_t)bin << shift);
      s_remaining = rem - acc;
    }
    __syncthreads();
  }
  const uint32_t T = s_prefix;

  // Collect all elements with key >= T (count >= K; ties beyond K dropped
  // after sort). Combined item: key desc primary, idx asc secondary.
  for (int i = t; i < N; i += 1024) {
    uint32_t k = keys[i];
    if (k >= T) {
      uint32_t pos = atomicAdd(&cand_cnt, 1u);
      if (pos < 512)
        cand[pos] = ((uint64_t)k << 32) | (uint64_t)(0xFFFFFFFFu - (uint32_t)i);
    }
  }
  __syncthreads();
  int cnt = (int)cand_cnt;
  if (cnt > 512) cnt = 512;
  if (t < 512 && t >= cnt) cand[t] = 0;  // pad
  __syncthreads();

  // Bitonic sort 512 items, descending.
  for (int ksz = 2; ksz <= 512; ksz <<= 1) {
    for (int j = ksz >> 1; j >= 1; j >>= 1) {
      if (t < 512) {
        int ixj = t ^ j;
        if (ixj > t) {
          uint64_t a = cand[t], c = cand[ixj];
          bool desc = ((t & ksz) == 0);
          if (desc ? (a < c) : (a > c)) {
            cand[t] = c;
            cand[ixj] = a;
          }
        }
      }
      __syncthreads();
    }
  }

  if (t < K) {
    int idx = (int)(0xFFFFFFFFu - (uint32_t)(cand[t] & 0xFFFFFFFFu));
    idx_out[b * K + t] = idx;
    out_idx_f[b * K + t] = (float)idx;
  }
}

// ---------------------------------------------------------------------------
// Kernel 3: gather selected token vectors. One wave per (b, r).
// ---------------------------------------------------------------------------
__global__ __launch_bounds__(256) void gather_kernel(
    const float* __restrict__ tokens, const int* __restrict__ idx,
    float* __restrict__ out0) {
  int gwave = (blockIdx.x * blockDim.x + threadIdx.x) >> 6;  // 0..B*K-1
  int lane = threadIdx.x & 63;
  if (gwave >= B * K) return;
  int b = gwave / K;
  int id = idx[gwave];
  float4 v = ((const float4*)(tokens + ((size_t)b * N + id) * D))[lane];
  ((float4*)(out0 + (size_t)gwave * D))[lane] = v;
}

extern "C" void kernel_launch(void* const* d_in, const int* in_sizes, int n_in,
                              void* d_out, int out_size, void* d_ws,
                              size_t ws_size, hipStream_t stream) {
  const float* tokens = (const float*)d_in[0];
  const float* W = (const float*)d_in[1];
  const float* bias = (const float*)d_in[2];

  float* out_sel = (float*)d_out;                    // [B, K, D] float32
  float* out_idx_f = out_sel + (size_t)B * K * D;    // [B, K] indices as float

  uint32_t* keys = (uint32_t*)d_ws;                          // B*N*4 = 1.28 MB
  int* idx = (int*)((char*)d_ws + (size_t)B * N * sizeof(uint32_t));  // B*K*4

  score_kernel<<<(B * N + 3) / 4, 256, 0, stream>>>(tokens, W, bias, keys);
  topk_kernel<<<B, 1024, 0, stream>>>(keys, idx, out_idx_f);
  gather_kernel<<<(B * K + 3) / 4, 256, 0, stream>>>(tokens, idx, out_sel);
}

// Round 2
// 448.711 us; speedup vs baseline: 1.0683x; 1.0683x over previous
//
#include <hip/hip_runtime.h>
#include <stdint.h>

#define B 16
#define N 20000
#define D 256
#define K 300

// ---------------------------------------------------------------------------
// Kernel 1: per-token score = dot(token, W) + b -> monotone uint32 key.
// One wave handles 4 tokens (4 independent float4 loads in flight per lane).
// Lane 0 stores 4 keys as one uint4.
// ---------------------------------------------------------------------------
__global__ __launch_bounds__(256) void score_kernel(
    const float* __restrict__ tokens, const float* __restrict__ W,
    const float* __restrict__ bias, uint32_t* __restrict__ keys) {
  int wid = (blockIdx.x * blockDim.x + threadIdx.x) >> 6;  // wave id
  int lane = threadIdx.x & 63;
  int tb = wid * 4;  // first of 4 tokens
  if (tb >= B * N) return;
  const float4 w4 = ((const float4*)W)[lane];
  const float4* tp = (const float4*)(tokens + (size_t)tb * D);
  float4 a0 = tp[lane];
  float4 a1 = tp[64 + lane];
  float4 a2 = tp[128 + lane];
  float4 a3 = tp[192 + lane];
  float d0 = a0.x * w4.x + a0.y * w4.y + a0.z * w4.z + a0.w * w4.w;
  float d1 = a1.x * w4.x + a1.y * w4.y + a1.z * w4.z + a1.w * w4.w;
  float d2 = a2.x * w4.x + a2.y * w4.y + a2.z * w4.z + a2.w * w4.w;
  float d3 = a3.x * w4.x + a3.y * w4.y + a3.z * w4.z + a3.w * w4.w;
#pragma unroll
  for (int off = 32; off >= 1; off >>= 1) {
    d0 += __shfl_xor(d0, off, 64);
    d1 += __shfl_xor(d1, off, 64);
    d2 += __shfl_xor(d2, off, 64);
    d3 += __shfl_xor(d3, off, 64);
  }
  if (lane == 0) {
    float bb = bias[0];
    float s0 = d0 + bb, s1 = d1 + bb, s2 = d2 + bb, s3 = d3 + bb;
    uint32_t u0 = __float_as_uint(s0), u1 = __float_as_uint(s1);
    uint32_t u2 = __float_as_uint(s2), u3 = __float_as_uint(s3);
    uint4 kv;
    kv.x = (u0 & 0x80000000u) ? ~u0 : (u0 | 0x80000000u);
    kv.y = (u1 & 0x80000000u) ? ~u1 : (u1 | 0x80000000u);
    kv.z = (u2 & 0x80000000u) ? ~u2 : (u2 | 0x80000000u);
    kv.w = (u3 & 0x80000000u) ? ~u3 : (u3 | 0x80000000u);
    ((uint4*)keys)[wid] = kv;
  }
}

// ---------------------------------------------------------------------------
// Kernel 2: per-batch top-K. MSB-first 4x8-bit radix select with wave-parallel
// suffix-scan of the 256-bin histogram; uint4 sweeps; collect >= threshold;
// bitonic sort 512 (key desc, idx asc); write idx + float(idx).
// One block of 1024 threads per batch.
// ---------------------------------------------------------------------------
__global__ __launch_bounds__(1024) void topk_kernel(
    const uint32_t* __restrict__ keys_g, int* __restrict__ idx_out,
    float* __restrict__ out_idx_f) {
  __shared__ __align__(16) uint32_t hist[256];
  __shared__ uint64_t cand[512];
  __shared__ uint32_t s_prefix, s_remaining, s_prefix_next, s_rem_next,
      cand_cnt;

  const int b = blockIdx.x;
  const int t = threadIdx.x;
  const uint4* keys4 = (const uint4*)(keys_g + (size_t)b * N);
  const int N4 = N / 4;  // 5000

  if (t == 0) {
    s_prefix = 0;
    s_remaining = K;
    cand_cnt = 0;
  }
  if (t < 256) hist[t] = 0;
  __syncthreads();

  for (int pass = 0; pass < 4; ++pass) {
    const int shift = 24 - pass * 8;
    const uint32_t prefix = s_prefix;
    const uint32_t pmask = (pass == 0) ? 0u : (0xFFFFFFFFu << (shift + 8));
    for (int i = t; i < N4; i += 1024) {
      uint4 kv = keys4[i];
      uint32_t ka[4] = {kv.x, kv.y, kv.z, kv.w};
#pragma unroll
      for (int j = 0; j < 4; ++j)
        if ((ka[j] & pmask) == prefix)
          atomicAdd(&hist[(ka[j] >> shift) & 255u], 1u);
    }
    __syncthreads();
    // Wave 0: parallel suffix-scan over 256 bins (4 bins per lane).
    if (t < 64) {
      uint4 h = ((const uint4*)hist)[t];
      uint32_t hv0 = h.x, hv1 = h.y, hv2 = h.z, hv3 = h.w;
      uint32_t sum4 = hv0 + hv1 + hv2 + hv3;
      uint32_t s = sum4;
#pragma unroll
      for (int off = 1; off < 64; off <<= 1) {
        uint32_t v = __shfl_down(s, off, 64);
        if (t + off < 64) s += v;
      }
      // s = count of keys in bins >= 4t (within current prefix)
      uint32_t rem = s_remaining;
      uint32_t acc = s - sum4;  // count in bins >= 4(t+1)
      uint32_t hv[4] = {hv0, hv1, hv2, hv3};
#pragma unroll
      for (int j = 3; j >= 0; --j) {
        uint32_t ge = acc + hv[j];
        if (acc < rem && rem <= ge) {
          s_prefix_next = prefix | ((uint32_t)(4 * t + j) << shift);
          s_rem_next = rem - acc;
        }
        acc = ge;
      }
    }
    __syncthreads();
    if (t == 0) {
      s_prefix = s_prefix_next;
      s_remaining = s_rem_next;
    }
    if (t < 256) hist[t] = 0;  // ready for next pass
    __syncthreads();
  }
  const uint32_t T = s_prefix;  // exact K-th largest key

  // Collect all keys >= T (count >= K, <= K + duplicates-of-T).
  for (int i = t; i < N4; i += 1024) {
    uint4 kv = keys4[i];
    uint32_t ka[4] = {kv.x, kv.y, kv.z, kv.w};
#pragma unroll
    for (int j = 0; j < 4; ++j)
      if (ka[j] >= T) {
        uint32_t pos = atomicAdd(&cand_cnt, 1u);
        if (pos < 512)
          cand[pos] = ((uint64_t)ka[j] << 32) |
                      (uint64_t)(0xFFFFFFFFu - (uint32_t)(4 * i + j));
      }
  }
  __syncthreads();
  int cnt = (int)cand_cnt;
  if (cnt > 512) cnt = 512;
  if (t < 512 && t >= cnt) cand[t] = 0;
  __syncthreads();

  // Bitonic sort 512 items descending (key desc, then idx asc via ~idx).
  for (int ksz = 2; ksz <= 512; ksz <<= 1) {
    for (int j = ksz >> 1; j >= 1; j >>= 1) {
      if (t < 512) {
        int ixj = t ^ j;
        if (ixj > t) {
          uint64_t a = cand[t], c = cand[ixj];
          bool desc = ((t & ksz) == 0);
          if (desc ? (a < c) : (a > c)) {
            cand[t] = c;
            cand[ixj] = a;
          }
        }
      }
      __syncthreads();
    }
  }

  if (t < K) {
    int idx = (int)(0xFFFFFFFFu - (uint32_t)(cand[t] & 0xFFFFFFFFu));
    idx_out[b * K + t] = idx;
    out_idx_f[b * K + t] = (float)idx;
  }
}

// ---------------------------------------------------------------------------
// Kernel 3: gather selected token vectors. One wave per (b, r).
// ---------------------------------------------------------------------------
__global__ __launch_bounds__(256) void gather_kernel(
    const float* __restrict__ tokens, const int* __restrict__ idx,
    float* __restrict__ out0) {
  int gwave = (blockIdx.x * blockDim.x + threadIdx.x) >> 6;  // 0..B*K-1
  int lane = threadIdx.x & 63;
  if (gwave >= B * K) return;
  int b = gwave / K;
  int id = idx[gwave];
  float4 v = ((const float4*)(tokens + ((size_t)b * N + id) * D))[lane];
  ((float4*)(out0 + (size_t)gwave * D))[lane] = v;
}

extern "C" void kernel_launch(void* const* d_in, const int* in_sizes, int n_in,
                              void* d_out, int out_size, void* d_ws,
                              size_t ws_size, hipStream_t stream) {
  const float* tokens = (const float*)d_in[0];
  const float* W = (const float*)d_in[1];
  const float* bias = (const float*)d_in[2];

  float* out_sel = (float*)d_out;                  // [B, K, D] float32
  float* out_idx_f = out_sel + (size_t)B * K * D;  // [B, K] indices as float

  uint32_t* keys = (uint32_t*)d_ws;  // B*N*4 = 1.28 MB
  int* idx = (int*)((char*)d_ws + (size_t)B * N * sizeof(uint32_t));

  // 4 tokens per wave, 4 waves per block -> 16 tokens/block.
  score_kernel<<<(B * N) / 16, 256, 0, stream>>>(tokens, W, bias, keys);
  topk_kernel<<<B, 1024, 0, stream>>>(keys, idx, out_idx_f);
  gather_kernel<<<(B * K + 3) / 4, 256, 0, stream>>>(tokens, idx, out_sel);
}